// Round 1
// 58.971 us; speedup vs baseline: 1.0230x; 1.0230x over previous
//
#include <hip/hip_runtime.h>

// out[o,k,h,m] = sum_{i,j} p[o,i,(h-1)%14, m+j] * w[i,k,j]
// p[q]=0 for q in {0,15}; p[q]=x[o,i,n,(q-2)%14], n=(h-1)%14
//
// Grid (8,14,2)=224 blocks, block 512 = kk2(0..15) x s(0..31).
// Each thread: i in [8s,8s+8), k in {kt*32+2kk2, +1}, ALL 14 m.
//
// R4 changes vs R3-best (latency-bound under cold caches from the 256MiB
// harness poison; dur_us 60.3 > max dispatch 40.8 proves fill is inside
// the timed region):
//  1. w prefetched into regs BEFORE the staging barrier -> x-stage and w
//     cold misses overlap (were serialized by the barrier's vmcnt(0) drain).
//  2. xs quad-XOR swizzle (col ^= (s&3)<<2): kills the 4-way ds_read_b128
//     bank conflict (4 s-groups at 512B stride hit identical banks).
//  3. part layout o'-major with stride 33: writes 2-way (free), reads
//     (t+si)%32 (free), and final out stores become m-contiguous 56B runs.

#define BT 512

__global__ __launch_bounds__(BT) void shiftconv_kernel(
    const float* __restrict__ x,   // (2,256,14,14)
    const float* __restrict__ w,   // (256,256,3)
    float* __restrict__ out)       // (2,256,14,14)
{
    __shared__ __align__(16) float smem[448 * 33];  // 59136 B
    float* xs   = smem;        // phase 1: 256 rows x 16 floats, quads swizzled
    float* part = smem;        // phase 2: part[o'*33 + s] (aliased, sync-separated)

    const int kt = blockIdx.x;   // 0..7
    const int h  = blockIdx.y;   // 0..13
    const int o  = blockIdx.z;   // 0..1
    const int t  = threadIdx.x;  // 0..511
    const int n  = (h + 13) % 14;

    const int kk2 = t & 15;      // k-pair index
    const int s   = t >> 4;      // 0..31 split-K
    const int kg0 = kt * 32 + 2 * kk2;
    const int i0  = s * 8;
    const int sq  = s & 3;       // quad-swizzle key for this thread's rows

    // ---- issue x loads first (7 per thread) ----
    float xv[7];
#pragma unroll
    for (int r = 0; r < 7; ++r) {
        int e  = t + r * BT;
        int i  = e / 14;
        int ww = e - i * 14;
        xv[r] = x[((size_t)(o * 256 + i) * 14 + n) * 14 + ww];
    }

    // ---- issue all w loads before the barrier: cold misses overlap x-stage ----
    const float* wp = w + ((size_t)i0 * 256 + kg0) * 3;  // 6 contig floats per i
    float3 wa[8], wb[8];
#pragma unroll
    for (int i = 0; i < 8; ++i) {
        wa[i] = *reinterpret_cast<const float3*>(wp);
        wb[i] = *reinterpret_cast<const float3*>(wp + 3);
        wp += 768;
    }

    // ---- zero pads + store x rows to LDS (quad-XOR swizzled by row>>3) ----
    {
        int rz = t >> 1;
        int cz = (t & 1) * 15;                       // cols 0 and 15 are the zero pads
        xs[rz * 16 + (cz ^ (((rz >> 3) & 3) << 2))] = 0.0f;
    }
#pragma unroll
    for (int r = 0; r < 7; ++r) {
        int e  = t + r * BT;
        int i  = e / 14;
        int ww = e - i * 14;
        int c  = (ww <= 12) ? (ww + 2) : 1;
        xs[i * 16 + (c ^ (((i >> 3) & 3) << 2))] = xv[r];
    }
    __syncthreads();

    float accA[14], accB[14];
#pragma unroll
    for (int m = 0; m < 14; ++m) { accA[m] = 0.f; accB[m] = 0.f; }

    const float* xp = xs + i0 * 16;
#pragma unroll
    for (int i = 0; i < 8; ++i) {
        // logical quad j lives at physical quad (j ^ sq): conflict-free b128
        float r[16];
#pragma unroll
        for (int j = 0; j < 4; ++j) {
            float4 q = *reinterpret_cast<const float4*>(xp + ((j ^ sq) << 2));
            r[4 * j + 0] = q.x; r[4 * j + 1] = q.y;
            r[4 * j + 2] = q.z; r[4 * j + 3] = q.w;
        }
#pragma unroll
        for (int m = 0; m < 14; ++m) {
            accA[m] = fmaf(r[m],     wa[i].x, accA[m]);
            accA[m] = fmaf(r[m + 1], wa[i].y, accA[m]);
            accA[m] = fmaf(r[m + 2], wa[i].z, accA[m]);
            accB[m] = fmaf(r[m],     wb[i].x, accB[m]);
            accB[m] = fmaf(r[m + 1], wb[i].y, accB[m]);
            accB[m] = fmaf(r[m + 2], wb[i].z, accB[m]);
        }
        xp += 16;
    }

    __syncthreads();   // all xs reads done before part overwrites it

    // ---- write split-K partials, output-major: o' = u*14 + m, u = 2*kk2 + {0,1} ----
    const int oA = (2 * kk2) * 14;
    const int oB = oA + 14;
#pragma unroll
    for (int m = 0; m < 14; ++m) {
        part[(oA + m) * 33 + s] = accA[m];   // banks: 2 lanes/bank (free)
        part[(oB + m) * 33 + s] = accB[m];
    }
    __syncthreads();

    // ---- reduce over s; coalesced store (m fastest across lanes) ----
    if (t < 448) {
        float s0 = 0.f, s1 = 0.f, s2 = 0.f, s3 = 0.f;
        const float* pr = part + t * 33;     // banks: (t+si)%32 -> 2-way, free
#pragma unroll
        for (int si = 0; si < 32; si += 4) {
            s0 += pr[si + 0];
            s1 += pr[si + 1];
            s2 += pr[si + 2];
            s3 += pr[si + 3];
        }
        int u = t / 14;                      // k within tile
        int m = t - u * 14;
        out[((size_t)(o * 256 + kt * 32 + u) * 14 + h) * 14 + m] = (s0 + s1) + (s2 + s3);
    }
}

extern "C" void kernel_launch(void* const* d_in, const int* in_sizes, int n_in,
                              void* d_out, int out_size, void* d_ws, size_t ws_size,
                              hipStream_t stream) {
    const float* x = (const float*)d_in[0];
    const float* w = (const float*)d_in[1];
    float* out = (float*)d_out;

    dim3 grid(8, 14, 2);
    dim3 block(BT);
    shiftconv_kernel<<<grid, block, 0, stream>>>(x, w, out);
}